// Round 6
// baseline (166.810 us; speedup 1.0000x reference)
//
#include <hip/hip_runtime.h>
#include <hip/hip_cooperative_groups.h>
#include <math.h>

namespace cg = cooperative_groups;

#define LL 8
#define AA 4
#define DD 256
#define KF 129            // frequencies 0..128
#define KH 128            // complex frequencies 0..127; k=128 real (Nyquist)
#define CLEN 32           // steps per chunk
#define NGR 128           // groups of 4 chunks (512 chunks total)
#define NES 36            // strict-lower entries, rows 1..8 (unit diagonal implicit)
#define LPAD 37           // padded slot stride (in elements)

typedef float v2f __attribute__((ext_vector_type(2)));

#define SIX(l2,l1) ((((l2)*((l2)-1))>>1) + (l1))     // l2 in 1..8, l1 < l2
#define SLOT(s)    ((s)*LPAD + ((s)>>1))             // complex slot base (v2f units)

// ws layout in floats (~4.8 MB)
#define Q_OFF   0
#define OPS_OFF (32*KF*2)                            // 8,256
#define OPS_SZ  (KH*NGR*NES*2)                       // 1,179,648
#define VH_OFF  (OPS_OFF + OPS_SZ)
#define V_OFF   (VH_OFF + 2*40)
#define CNT_OFF (V_OFF + 2*KF)                       // 2 ints

// T-space rescale: S_d[l] = T_d[l] / C(d,l); output row 8 needs 1/C(16384,8)
__device__ __forceinline__ float invCN8() {
  constexpr double c = (16384.0 * 16383.0 * 16382.0 * 16381.0 *
                        16380.0 * 16379.0 * 16378.0 * 16377.0) / 40320.0;
  return (float)(1.0 / c);
}

// acc += b (complex mul) a   -- packed: 2x v_pk_fma_f32
__device__ __forceinline__ v2f cfma(const v2f b, const v2f a, v2f acc) {
  const v2f bb = (v2f){ b.x,  b.x};
  const v2f bw = (v2f){-b.y,  b.y};
  const v2f as = (v2f){ a.y,  a.x};
  acc = __builtin_elementwise_fma(bb, a,  acc);
  acc = __builtin_elementwise_fma(bw, as, acc);
  return acc;
}

// packed T-space step: G[l][l1] += Q_l (x) G[l-1][l1], unit diag
template <int CC>
__device__ __forceinline__ void tstep2(v2f (&G)[NES],
                                       const v2f (&QA)[LL][AA], const v2f (&QB)[LL][AA]) {
#pragma unroll
  for (int l = LL; l >= 1; --l) {          // descending: row l reads OLD row l-1
    const v2f qa = QA[l - 1][CC];          // (qr, qr)
    const v2f qb = QB[l - 1][CC];          // (-qi, qi)
    {
      v2f g = G[SIX(l, l - 1)];
      g.x += qa.x; g.y += qb.y;
      G[SIX(l, l - 1)] = g;
    }
#pragma unroll
    for (int l1 = 0; l1 < l - 1; ++l1) {
      const v2f H  = G[SIX(l - 1, l1)];
      const v2f Hs = (v2f){H.y, H.x};
      v2f g = G[SIX(l, l1)];
      g = __builtin_elementwise_fma(qa, H,  g);
      g = __builtin_elementwise_fma(qb, Hs, g);
      G[SIX(l, l1)] = g;
    }
  }
}

// column-split product of unit-lower-triangular ops: C = B*A (B is the later op)
template <unsigned MASK>
__device__ __forceinline__ void prodCols(const v2f* __restrict__ A, const v2f* __restrict__ B,
                                         v2f (&o)[NES]) {
#pragma unroll
  for (int l1 = 0; l1 < 8; ++l1) {
    if ((MASK >> l1) & 1) {
#pragma unroll
      for (int l2 = l1 + 1; l2 <= 8; ++l2) {
        v2f acc = A[SIX(l2, l1)] + B[SIX(l2, l1)];
#pragma unroll
        for (int m = l1 + 1; m < l2; ++m) acc = cfma(B[SIX(l2, m)], A[SIX(m, l1)], acc);
        o[SIX(l2, l1)] = acc;
      }
    }
  }
}

template <unsigned MASK>
__device__ __forceinline__ void writeCols(v2f* __restrict__ D, const v2f (&o)[NES]) {
#pragma unroll
  for (int l1 = 0; l1 < 8; ++l1) {
    if ((MASK >> l1) & 1) {
#pragma unroll
      for (int l2 = l1 + 1; l2 <= 8; ++l2) D[SIX(l2, l1)] = o[SIX(l2, l1)];
    }
  }
}

// real (Nyquist) full product, strict-lower unit-triangular
__device__ __forceinline__ void prodR(const float* __restrict__ A, const float* __restrict__ B,
                                      float (&o)[NES]) {
#pragma unroll
  for (int l1 = 0; l1 < 8; ++l1) {
#pragma unroll
    for (int l2 = l1 + 1; l2 <= 8; ++l2) {
      float acc = A[SIX(l2, l1)] + B[SIX(l2, l1)];
#pragma unroll
      for (int m = l1 + 1; m < l2; ++m) acc = fmaf(B[SIX(l2, m)], A[SIX(m, l1)], acc);
      o[SIX(l2, l1)] = acc;
    }
  }
}

// ---------------- fused kernel: 256 blocks x 256 threads, cooperative ------------------------
__global__ __launch_bounds__(256, 1) void kfused(const int* __restrict__ seq,
                                                 const float* __restrict__ hemb,
                                                 const float* __restrict__ slog,
                                                 float* __restrict__ Q,
                                                 float* __restrict__ opsT,
                                                 float* __restrict__ vh,
                                                 float* __restrict__ v,
                                                 int* __restrict__ cnt,
                                                 float* __restrict__ outp) {
  cg::grid_group grid = cg::this_grid();
  const int blk = blockIdx.x;          // 0..255
  const int t   = threadIdx.x;         // 0..255
  __shared__ __align__(16) float ldsf[9600];   // 38400 B, phase-aliased

  if (blk == 0 && t == 0) {
    __hip_atomic_store(&cnt[0], 0, __ATOMIC_RELEASE, __HIP_MEMORY_SCOPE_AGENT);
    __hip_atomic_store(&cnt[1], 0, __ATOMIC_RELEASE, __HIP_MEMORY_SCOPE_AGENT);
  }

  // ================= Phase A: Q[l][c][k] (blocks 0..31) =================
  if (blk < LL * AA) {
    const int b = blk;
    float*  sh  = ldsf;                    // [256]
    float*  red = ldsf + 256;              // [256]
    float2* tw  = (float2*)(ldsf + 512);   // [256]
    {
      float sn, cs;
      __sincosf((float)t * (-0.0245436926061702596754894014319f), &sn, &cs); // -2*pi/256
      tw[t] = make_float2(cs, sn);
    }
    float h = hemb[b * DD + t];
    red[t] = h; __syncthreads();
    for (int off = 128; off > 0; off >>= 1) {
      if (t < off) red[t] = fmaxf(red[t], red[t + off]);
      __syncthreads();
    }
    float mx = red[0]; __syncthreads();
    float e = expf(h - mx);
    red[t] = e; __syncthreads();
    for (int off = 128; off > 0; off >>= 1) {
      if (t < off) red[t] += red[t + off];
      __syncthreads();
    }
    float s = red[0];
    sh[t] = e / s;
    __syncthreads();
    if (t < KF) {
      float cr = 0.0f, ci = 0.0f;
      for (int j = 0; j < DD; ++j) {
        const int m = (t * j) & 255;
        const float2 w = tw[m];
        const float p = sh[j];
        cr = fmaf(p, w.x, cr);
        ci = fmaf(p, w.y, ci);
      }
      const float sl = slog[b];
      const float sg = 1.0f / (1.0f + expf(-sl));
      const float q = fmaf(2.0f, sg, -1.0f);
      Q[(b * KF + t) * 2 + 0] = q * cr;
      Q[(b * KF + t) * 2 + 1] = q * ci;
    }
    __syncthreads();   // LDS reuse safety before grid-wide phase switch
  }

  grid.sync();

  // ================= Phase B: group transfer operators (all 256 blocks) =================
  {
    const int g    = blk >> 1;            // group 0..127
    const int half = blk & 1;
    const int w    = t >> 6;              // wave 0..3
    const int lane = t & 63;
    const int k    = half * 64 + lane;

    v2f* S0 = (v2f*)ldsf;                 // [64 slots][LPAD]
    v2f* S1 = S0 + 64 * LPAD;

    v2f QA[LL][AA], QB[LL][AA];
    const float2* Q2 = (const float2*)Q;
#pragma unroll
    for (int lc = 0; lc < LL * AA; ++lc) {
      const float2 q = Q2[lc * KF + k];
      QA[lc >> 2][lc & 3] = (v2f){ q.x, q.x};
      QB[lc >> 2][lc & 3] = (v2f){-q.y, q.y};
    }

    v2f G[NES];
#pragma unroll
    for (int e = 0; e < NES; ++e) G[e] = (v2f){0.f, 0.f};   // identity op

    const int chunk = g * 4 + w;
    const int base  = chunk * CLEN;
    const int myc   = seq[base + (lane & 31)];
    for (int s2 = 0; s2 < CLEN; ++s2) {
      const int c = __builtin_amdgcn_readlane(myc, s2);
      switch (c) {
        case 0:  tstep2<0>(G, QA, QB); break;
        case 1:  tstep2<1>(G, QA, QB); break;
        case 2:  tstep2<2>(G, QA, QB); break;
        default: tstep2<3>(G, QA, QB); break;
      }
    }

    // in-block combine: P = O3*O2*O1*O0, 4-way column split across waves
    const v2f* Ab = S0 + lane * LPAD;
    const v2f* Bb = S1 + lane * LPAD;
    v2f* Db = S0 + lane * LPAD;
    v2f* Wb = S1 + lane * LPAD;
    v2f pc[NES];

    if (w == 0)      { for (int e = 0; e < NES; ++e) Db[e] = G[e]; }
    else if (w == 1) { for (int e = 0; e < NES; ++e) Wb[e] = G[e]; }
    __syncthreads();

    for (int r = 0; r < 3; ++r) {
      switch (w) {
        case 0:  prodCols<0x01>(Ab, Bb, pc); break;   // col {0}
        case 1:  prodCols<0x42>(Ab, Bb, pc); break;   // cols {1,6}
        case 2:  prodCols<0x14>(Ab, Bb, pc); break;   // cols {2,4}
        default: prodCols<0xA8>(Ab, Bb, pc); break;   // cols {3,5,7}
      }
      __syncthreads();
      switch (w) {
        case 0:  writeCols<0x01>(Db, pc); break;
        case 1:  writeCols<0x42>(Db, pc); break;
        case 2:  writeCols<0x14>(Db, pc); break;
        default: writeCols<0xA8>(Db, pc); break;
      }
      if ((r == 0 && w == 2) || (r == 1 && w == 3)) {
        for (int e = 0; e < NES; ++e) Wb[e] = G[e];
      }
      __syncthreads();
    }

    // staging copy S0 -> global opsT[k][g][e]
    float2* dst = (float2*)opsT;
    for (int it = 0; it < 9; ++it) {
      const int idx = it * 256 + t;           // 0..2303 = 64 ops * 36 entries
      const int o   = idx / 36;
      const int e   = idx - o * 36;
      const v2f x   = S0[o * LPAD + e];
      dst[((size_t)(half * 64 + o) * NGR + g) * NES + e] = make_float2(x.x, x.y);
    }
    __syncthreads();
  }

  grid.sync();

  // ================= Phase C: reduction + Nyquist + last-block DFT (blocks 0..129) =========
  if (blk < KH + 2) {
    if (blk < KH) {
      // complex path, k = blk
      const int k = blk;
      v2f* L = (v2f*)ldsf;
      const float4* src4 = (const float4*)(opsT + (size_t)k * NGR * NES * 2);
      for (int it = 0; it < 9; ++it) {
        const int idx = it * 256 + t;        // 2304 float4 total
        const float4 x = src4[idx];
        const int o = idx / 18;              // 18 float4 per op
        const int u = idx - o * 18;
        L[SLOT(o) + 2 * u]     = (v2f){x.x, x.y};
        L[SLOT(o) + 2 * u + 1] = (v2f){x.z, x.w};
      }
      __syncthreads();

      const int w = t >> 6;
      const int j = t & 63;
      v2f pc[NES];
      for (int n = 64; n >= 8; n >>= 1) {    // 128->64->32->16->8 ops
        const bool act = (j < n);
        if (act) {
          const v2f* Ab = L + SLOT(2 * j);
          const v2f* Bb = L + SLOT(2 * j + 1);
          switch (w) {
            case 0:  prodCols<0x01>(Ab, Bb, pc); break;
            case 1:  prodCols<0x42>(Ab, Bb, pc); break;
            case 2:  prodCols<0x14>(Ab, Bb, pc); break;
            default: prodCols<0xA8>(Ab, Bb, pc); break;
          }
        }
        __syncthreads();
        if (act) {
          v2f* Db = L + SLOT(j);
          switch (w) {
            case 0:  writeCols<0x01>(Db, pc); break;
            case 1:  writeCols<0x42>(Db, pc); break;
            case 2:  writeCols<0x14>(Db, pc); break;
            default: writeCols<0xA8>(Db, pc); break;
          }
        }
        __syncthreads();
      }

      // apply 8 remaining ops to e0 (wave 0; lane l holds row l, shfl broadcast)
      if (t < 64) {
        v2f sv[LL + 1];
        sv[0] = (v2f){1.f, 0.f};
#pragma unroll
        for (int l = 1; l <= LL; ++l) sv[l] = (v2f){0.f, 0.f};
        for (int gg = 0; gg < 8; ++gg) {
          v2f nv = (v2f){0.f, 0.f};
          if (t >= 1 && t <= LL) {
            nv = sv[t];                               // unit diagonal
            const v2f* Bb = L + SLOT(gg);
            const int rb = (t * (t - 1)) >> 1;        // SIX(t, 0)
#pragma unroll
            for (int l1 = 0; l1 < 8; ++l1) {
              if (l1 < t) nv = cfma(Bb[rb + l1], sv[l1], nv);
            }
          }
#pragma unroll
          for (int l = 1; l <= LL; ++l) {
            sv[l].x = __shfl(nv.x, l);
            sv[l].y = __shfl(nv.y, l);
          }
        }
        if (t == 0) {
          __hip_atomic_store(&v[2 * k],     sv[LL].x, __ATOMIC_RELEASE, __HIP_MEMORY_SCOPE_AGENT);
          __hip_atomic_store(&v[2 * k + 1], sv[LL].y, __ATOMIC_RELEASE, __HIP_MEMORY_SCOPE_AGENT);
        }
      }
    } else {
      // Nyquist (k=128, real): blocks 128,129 = halves
      const int half = blk - KH;
      float* Lr = ldsf;                       // [256 slots][LPAD] floats
      float Q8[LL][AA];
#pragma unroll
      for (int lc = 0; lc < LL * AA; ++lc) Q8[lc >> 2][lc & 3] = Q[(lc * KF + KH) * 2];

      float Gr[NES];
#pragma unroll
      for (int e = 0; e < NES; ++e) Gr[e] = 0.f;

      const int base = (half * 256 + t) * CLEN;
      int sym[CLEN];
      {
        const int4* sp = (const int4*)(seq + base);
#pragma unroll
        for (int u = 0; u < CLEN / 4; ++u) {
          const int4 x = sp[u];
          sym[4 * u + 0] = x.x; sym[4 * u + 1] = x.y;
          sym[4 * u + 2] = x.z; sym[4 * u + 3] = x.w;
        }
      }
#pragma unroll
      for (int s2 = 0; s2 < CLEN; ++s2) {
        const int c = sym[s2];
        float Qs[LL];
#pragma unroll
        for (int l = 0; l < LL; ++l) {
          const float qa = (c & 1) ? Q8[l][1] : Q8[l][0];
          const float qb = (c & 1) ? Q8[l][3] : Q8[l][2];
          Qs[l] = (c & 2) ? qb : qa;
        }
#pragma unroll
        for (int l = LL; l >= 1; --l) {
          Gr[SIX(l, l - 1)] += Qs[l - 1];
#pragma unroll
          for (int l1 = 0; l1 < l - 1; ++l1)
            Gr[SIX(l, l1)] = fmaf(Qs[l - 1], Gr[SIX(l - 1, l1)], Gr[SIX(l, l1)]);
        }
      }
#pragma unroll
      for (int e = 0; e < NES; ++e) Lr[t * LPAD + e] = Gr[e];
      __syncthreads();

      float po[NES];
      for (int n = 128; n >= 1; n >>= 1) {   // 256 -> 1
        const bool act = (t < n);
        if (act) prodR(Lr + (2 * t) * LPAD, Lr + (2 * t + 1) * LPAD, po);
        __syncthreads();
        if (act) { for (int e = 0; e < NES; ++e) Lr[t * LPAD + e] = po[e]; }
        __syncthreads();
      }
      if (t < NES)
        __hip_atomic_store(&vh[half * 40 + t], Lr[t], __ATOMIC_RELEASE, __HIP_MEMORY_SCOPE_AGENT);
      __syncthreads();
      if (t == 0) {
        const int o2 = __hip_atomic_fetch_add(&cnt[1], 1, __ATOMIC_ACQ_REL, __HIP_MEMORY_SCOPE_AGENT);
        if (o2 == 1) {
          // second arriving half: row 8, column 0 of H1*H0
          float h0[LL + 1];
#pragma unroll
          for (int m = 1; m <= LL; ++m)
            h0[m] = __hip_atomic_load(&vh[0 + SIX(m, 0)], __ATOMIC_ACQUIRE, __HIP_MEMORY_SCOPE_AGENT);
          float acc = h0[LL] +
            __hip_atomic_load(&vh[40 + SIX(LL, 0)], __ATOMIC_ACQUIRE, __HIP_MEMORY_SCOPE_AGENT);
#pragma unroll
          for (int m = 1; m <= 7; ++m)
            acc = fmaf(__hip_atomic_load(&vh[40 + SIX(LL, m)], __ATOMIC_ACQUIRE, __HIP_MEMORY_SCOPE_AGENT),
                       h0[m], acc);
          __hip_atomic_store(&v[2 * KH],     acc,  __ATOMIC_RELEASE, __HIP_MEMORY_SCOPE_AGENT);
          __hip_atomic_store(&v[2 * KH + 1], 0.0f, __ATOMIC_RELEASE, __HIP_MEMORY_SCOPE_AGENT);
        }
      }
    }

    // last arriving of the 130 phase-C blocks performs the inverse real DFT
    __shared__ int isLast;
    __syncthreads();
    if (t == 0) {
      const int old = __hip_atomic_fetch_add(&cnt[0], 1, __ATOMIC_ACQ_REL, __HIP_MEMORY_SCOPE_AGENT);
      isLast = (old == KH + 1) ? 1 : 0;
    }
    __syncthreads();
    if (isLast) {
      __shared__ float2 twd[256];
      __shared__ float dvr[KF], dvi[KF];
      {
        float sn, cs;
        __sincosf((float)t * 0.0245436926061702596754894014319f, &sn, &cs);  // +2*pi/256
        twd[t] = make_float2(cs, sn);
      }
      if (t < KF) {
        dvr[t] = __hip_atomic_load(&v[2 * t],     __ATOMIC_ACQUIRE, __HIP_MEMORY_SCOPE_AGENT);
        dvi[t] = __hip_atomic_load(&v[2 * t + 1], __ATOMIC_ACQUIRE, __HIP_MEMORY_SCOPE_AGENT);
      }
      if (t == 0) {  // self-reset so every dispatch (incl. rocprof replays) starts clean
        __hip_atomic_store(&cnt[0], 0, __ATOMIC_RELEASE, __HIP_MEMORY_SCOPE_AGENT);
        __hip_atomic_store(&cnt[1], 0, __ATOMIC_RELEASE, __HIP_MEMORY_SCOPE_AGENT);
      }
      __syncthreads();
      const float sc = (1.0f / 256.0f) * invCN8();   // undo T-space rescale
      float sum = dvr[0] + ((t & 1) ? -dvr[KH] : dvr[KH]);
      for (int k2 = 1; k2 < KH; ++k2) {
        const int m = (t * k2) & 255;
        const float2 wv = twd[m];
        sum = fmaf(2.0f * dvr[k2], wv.x, sum);
        sum = fmaf(-2.0f * dvi[k2], wv.y, sum);
      }
      outp[t] = sum * sc;
    }
  }
}

extern "C" void kernel_launch(void* const* d_in, const int* in_sizes, int n_in,
                              void* d_out, int out_size, void* d_ws, size_t ws_size,
                              hipStream_t stream) {
  (void)in_sizes; (void)n_in; (void)out_size; (void)ws_size;
  const int*   seq  = (const int*)d_in[0];
  const float* hemb = (const float*)d_in[1];
  const float* slog = (const float*)d_in[2];
  float* ws   = (float*)d_ws;
  float* Q    = ws + Q_OFF;
  float* opsT = ws + OPS_OFF;
  float* vh   = ws + VH_OFF;
  float* v    = ws + V_OFF;
  int*   cnt  = (int*)(ws + CNT_OFF);
  float* o    = (float*)d_out;

  void* args[] = { (void*)&seq, (void*)&hemb, (void*)&slog, (void*)&Q, (void*)&opsT,
                   (void*)&vh, (void*)&v, (void*)&cnt, (void*)&o };
  hipLaunchCooperativeKernel((const void*)kfused, dim3(256), dim3(256), args, 0, stream);
}

// Round 7
// 98.456 us; speedup vs baseline: 1.6943x; 1.6943x over previous
//
#include <hip/hip_runtime.h>
#include <math.h>

#define LL 8
#define AA 4
#define DD 256
#define KF 129            // frequencies 0..128
#define KH 128            // complex frequencies 0..127; k=128 real (Nyquist)
#define CLEN 64           // steps per chunk (one chunk per thread)
#define NCH 256           // chunks (= threads per block)
#define NES 36            // strict-lower entries, rows 1..8 (unit diagonal implicit)
#define LPAD 37           // padded slot stride

typedef float v2f __attribute__((ext_vector_type(2)));

#define SIX(l2,l1) ((((l2)*((l2)-1))>>1) + (l1))     // l2 in 1..8, l1 < l2
#define SLOT(s)    ((s)*LPAD + ((s)>>1))             // complex slot base (v2f units)

// ws layout in floats (~10 KB)
#define Q_OFF   0
#define V_OFF   (32*KF*2)
#define CNT_OFF (V_OFF + 2*KF)                       // 2 ints

// T-space rescale: S_d[l] = T_d[l] / C(d,l); output row 8 needs 1/C(16384,8)
__device__ __forceinline__ float invCN8() {
  constexpr double c = (16384.0 * 16383.0 * 16382.0 * 16381.0 *
                        16380.0 * 16379.0 * 16378.0 * 16377.0) / 40320.0;
  return (float)(1.0 / c);
}

// acc += b (complex mul) a   -- packed
__device__ __forceinline__ v2f cfma(const v2f b, const v2f a, v2f acc) {
  const v2f bb = (v2f){ b.x,  b.x};
  const v2f bw = (v2f){-b.y,  b.y};
  const v2f as = (v2f){ a.y,  a.x};
  acc = __builtin_elementwise_fma(bb, a,  acc);
  acc = __builtin_elementwise_fma(bw, as, acc);
  return acc;
}

// column-split product of unit-lower-triangular ops: C = B*A (B is the later op)
template <unsigned MASK>
__device__ __forceinline__ void prodCols(const v2f* __restrict__ A, const v2f* __restrict__ B,
                                         v2f (&o)[NES]) {
#pragma unroll
  for (int l1 = 0; l1 < 8; ++l1) {
    if ((MASK >> l1) & 1) {
#pragma unroll
      for (int l2 = l1 + 1; l2 <= 8; ++l2) {
        v2f acc = A[SIX(l2, l1)] + B[SIX(l2, l1)];
#pragma unroll
        for (int m = l1 + 1; m < l2; ++m) acc = cfma(B[SIX(l2, m)], A[SIX(m, l1)], acc);
        o[SIX(l2, l1)] = acc;
      }
    }
  }
}

template <unsigned MASK>
__device__ __forceinline__ void writeCols(v2f* __restrict__ D, const v2f (&o)[NES]) {
#pragma unroll
  for (int l1 = 0; l1 < 8; ++l1) {
    if ((MASK >> l1) & 1) {
#pragma unroll
      for (int l2 = l1 + 1; l2 <= 8; ++l2) D[SIX(l2, l1)] = o[SIX(l2, l1)];
    }
  }
}

// full product with register-array A (earlier) and LDS B (later): o = B*A
__device__ __forceinline__ void prodFullRA(const v2f (&A)[NES], const v2f* __restrict__ B,
                                           v2f (&o)[NES]) {
#pragma unroll
  for (int l1 = 0; l1 < 8; ++l1) {
#pragma unroll
    for (int l2 = l1 + 1; l2 <= 8; ++l2) {
      v2f acc = A[SIX(l2, l1)] + B[SIX(l2, l1)];
#pragma unroll
      for (int m = l1 + 1; m < l2; ++m) acc = cfma(B[SIX(l2, m)], A[SIX(m, l1)], acc);
      o[SIX(l2, l1)] = acc;
    }
  }
}

// real full product, strict-lower unit-triangular
__device__ __forceinline__ void prodR(const float* __restrict__ A, const float* __restrict__ B,
                                      float (&o)[NES]) {
#pragma unroll
  for (int l1 = 0; l1 < 8; ++l1) {
#pragma unroll
    for (int l2 = l1 + 1; l2 <= 8; ++l2) {
      float acc = A[SIX(l2, l1)] + B[SIX(l2, l1)];
#pragma unroll
      for (int m = l1 + 1; m < l2; ++m) acc = fmaf(B[SIX(l2, m)], A[SIX(m, l1)], acc);
      o[SIX(l2, l1)] = acc;
    }
  }
}

// ---------------- kernel 0: Q[l][c][k] -------------------------------------------------------
__global__ __launch_bounds__(256) void kq(const float* __restrict__ hemb,
                                          const float* __restrict__ slog,
                                          float* __restrict__ Q,
                                          int* __restrict__ cnt) {
  const int b = blockIdx.x;   // b = l*4 + c
  const int t = threadIdx.x;
  if (b == 0 && t == 0)
    __hip_atomic_store(&cnt[0], 0, __ATOMIC_RELEASE, __HIP_MEMORY_SCOPE_AGENT);
  __shared__ float sh[DD];
  __shared__ float red[256];
  __shared__ float2 tw[256];
  {
    float sn, cs;
    __sincosf((float)t * (-0.0245436926061702596754894014319f), &sn, &cs); // -2*pi/256
    tw[t] = make_float2(cs, sn);
  }
  float h = hemb[b * DD + t];
  red[t] = h; __syncthreads();
  for (int off = 128; off > 0; off >>= 1) {
    if (t < off) red[t] = fmaxf(red[t], red[t + off]);
    __syncthreads();
  }
  float mx = red[0]; __syncthreads();
  float e = expf(h - mx);
  red[t] = e; __syncthreads();
  for (int off = 128; off > 0; off >>= 1) {
    if (t < off) red[t] += red[t + off];
    __syncthreads();
  }
  float s = red[0];
  sh[t] = e / s;
  __syncthreads();
  if (t < KF) {
    float cr = 0.0f, ci = 0.0f;
    for (int j = 0; j < DD; ++j) {
      const int m = (t * j) & 255;
      const float2 w = tw[m];
      const float p = sh[j];
      cr = fmaf(p, w.x, cr);
      ci = fmaf(p, w.y, ci);
    }
    const float sl = slog[b];
    const float sg = 1.0f / (1.0f + expf(-sl));
    const float q = fmaf(2.0f, sg, -1.0f);
    Q[(b * KF + t) * 2 + 0] = q * cr;
    Q[(b * KF + t) * 2 + 1] = q * ci;
  }
}

// ---------------- kernel 1: per-frequency everything -----------------------------------------
// 129 blocks x 256 thr. Block k<128: thread t runs chunk t (64 steps) for freq k with
// LDS Q-table lookups; level-1 pair combine; column-split tree 128->8; apply to e0.
// Block 128: Nyquist real path. Last-arriving block does the inverse DFT.
__global__ __launch_bounds__(256, 1) void kmain(const int* __restrict__ seq,
                                                const float* __restrict__ Q,
                                                float* __restrict__ v,
                                                int* __restrict__ cnt,
                                                float* __restrict__ outp) {
  const int blk = blockIdx.x;    // 0..128
  const int t   = threadIdx.x;   // 0..255
  __shared__ __align__(16) float ldsf[9600];   // 38400 B: 128 complex slots / 256 real slots
  __shared__ __align__(16) float4 qtab[LL * AA];

  if (blk < KH) {
    // ================= complex path, k = blk =================
    const int k = blk;
    const float2* Q2 = (const float2*)Q;
    if (t < LL * AA) {
      const float2 q = Q2[t * KF + k];
      qtab[t] = make_float4(q.x, q.x, -q.y, q.y);   // (qr, qr, -qi, qi)
    }
    __syncthreads();

    // ---- chunk phase: 64 steps, symbols per-lane, Q via LDS table ----
    v2f G[NES];
#pragma unroll
    for (int e = 0; e < NES; ++e) G[e] = (v2f){0.f, 0.f};   // identity op

    const int4* sp = (const int4*)(seq + t * CLEN);
    for (int sb = 0; sb < CLEN / 4; ++sb) {
      const int4 cs = sp[sb];
      const int csy[4] = {cs.x, cs.y, cs.z, cs.w};
#pragma unroll
      for (int u = 0; u < 4; ++u) {
        const int c = csy[u];
        float4 qv[LL];
#pragma unroll
        for (int l = 0; l < LL; ++l) qv[l] = qtab[(l << 2) | c];
#pragma unroll
        for (int l = LL; l >= 1; --l) {          // descending: row l reads OLD row l-1
          const float4 q4 = qv[l - 1];
          const v2f qa = (v2f){q4.x, q4.y};      // (qr, qr)
          const v2f qb = (v2f){q4.z, q4.w};      // (-qi, qi)
          {
            v2f g = G[SIX(l, l - 1)];
            g.x += q4.x; g.y += q4.w;            // += (qr, qi)
            G[SIX(l, l - 1)] = g;
          }
#pragma unroll
          for (int l1 = 0; l1 < l - 1; ++l1) {
            const v2f H  = G[SIX(l - 1, l1)];
            const v2f Hs = (v2f){H.y, H.x};
            v2f g = G[SIX(l, l1)];
            g = __builtin_elementwise_fma(qa, H,  g);
            g = __builtin_elementwise_fma(qb, Hs, g);
            G[SIX(l, l1)] = g;
          }
        }
      }
    }

    // ---- level 1: 256 ops -> 128 slots in LDS ----
    v2f* L = (v2f*)ldsf;
    if (t & 1) {                       // odd chunk (later of the pair) -> LDS
      v2f* D = L + SLOT(t >> 1);
#pragma unroll
      for (int e = 0; e < NES; ++e) D[e] = G[e];
    }
    __syncthreads();
    if (!(t & 1)) {                    // even chunk combines: C = B(odd) * A(even)
      v2f o[NES];
      prodFullRA(G, L + SLOT(t >> 1), o);
      v2f* D = L + SLOT(t >> 1);
#pragma unroll
      for (int e = 0; e < NES; ++e) D[e] = o[e];
    }
    __syncthreads();

    // ---- column-split tree: 128 -> 64 -> 32 -> 16 -> 8 ----
    const int w = t >> 6;
    const int j = t & 63;
    v2f pc[NES];
    for (int n = 64; n >= 8; n >>= 1) {
      const bool act = (j < n);
      if (act) {
        const v2f* Ab = L + SLOT(2 * j);
        const v2f* Bb = L + SLOT(2 * j + 1);
        switch (w) {
          case 0:  prodCols<0x01>(Ab, Bb, pc); break;
          case 1:  prodCols<0x42>(Ab, Bb, pc); break;
          case 2:  prodCols<0x14>(Ab, Bb, pc); break;
          default: prodCols<0xA8>(Ab, Bb, pc); break;
        }
      }
      __syncthreads();
      if (act) {
        v2f* Db = L + SLOT(j);
        switch (w) {
          case 0:  writeCols<0x01>(Db, pc); break;
          case 1:  writeCols<0x42>(Db, pc); break;
          case 2:  writeCols<0x14>(Db, pc); break;
          default: writeCols<0xA8>(Db, pc); break;
        }
      }
      __syncthreads();
    }

    // ---- apply 8 remaining ops to e0 (wave 0; lane l holds row l) ----
    if (t < 64) {
      v2f sv[LL + 1];
      sv[0] = (v2f){1.f, 0.f};
#pragma unroll
      for (int l = 1; l <= LL; ++l) sv[l] = (v2f){0.f, 0.f};
      for (int gg = 0; gg < 8; ++gg) {
        v2f nv = (v2f){0.f, 0.f};
        if (t >= 1 && t <= LL) {
          nv = sv[t];                               // unit diagonal
          const v2f* Bb = L + SLOT(gg);
          const int rb = (t * (t - 1)) >> 1;        // SIX(t, 0)
#pragma unroll
          for (int l1 = 0; l1 < 8; ++l1) {
            if (l1 < t) nv = cfma(Bb[rb + l1], sv[l1], nv);
          }
        }
#pragma unroll
        for (int l = 1; l <= LL; ++l) {
          sv[l].x = __shfl(nv.x, l);
          sv[l].y = __shfl(nv.y, l);
        }
      }
      if (t == 0) {
        __hip_atomic_store(&v[2 * k],     sv[LL].x, __ATOMIC_RELEASE, __HIP_MEMORY_SCOPE_AGENT);
        __hip_atomic_store(&v[2 * k + 1], sv[LL].y, __ATOMIC_RELEASE, __HIP_MEMORY_SCOPE_AGENT);
      }
    }
  } else {
    // ================= Nyquist (k = 128, real) =================
    float* Lr = ldsf;                       // [256 slots][LPAD] floats
    float Q8[LL][AA];
#pragma unroll
    for (int lc = 0; lc < LL * AA; ++lc) Q8[lc >> 2][lc & 3] = Q[(lc * KF + KH) * 2];

    float Gr[NES];
#pragma unroll
    for (int e = 0; e < NES; ++e) Gr[e] = 0.f;

    const int4* sp = (const int4*)(seq + t * CLEN);
    for (int sb = 0; sb < CLEN / 4; ++sb) {
      const int4 cs = sp[sb];
      const int csy[4] = {cs.x, cs.y, cs.z, cs.w};
#pragma unroll
      for (int u = 0; u < 4; ++u) {
        const int c = csy[u];
        float Qs[LL];
#pragma unroll
        for (int l = 0; l < LL; ++l) {
          const float qa = (c & 1) ? Q8[l][1] : Q8[l][0];
          const float qb = (c & 1) ? Q8[l][3] : Q8[l][2];
          Qs[l] = (c & 2) ? qb : qa;
        }
#pragma unroll
        for (int l = LL; l >= 1; --l) {
          Gr[SIX(l, l - 1)] += Qs[l - 1];
#pragma unroll
          for (int l1 = 0; l1 < l - 1; ++l1)
            Gr[SIX(l, l1)] = fmaf(Qs[l - 1], Gr[SIX(l - 1, l1)], Gr[SIX(l, l1)]);
        }
      }
    }
#pragma unroll
    for (int e = 0; e < NES; ++e) Lr[t * LPAD + e] = Gr[e];
    __syncthreads();

    float po[NES];
    for (int n = 128; n >= 1; n >>= 1) {   // 256 -> 1 in-place pair tree
      const bool act = (t < n);
      if (act) prodR(Lr + (2 * t) * LPAD, Lr + (2 * t + 1) * LPAD, po);
      __syncthreads();
      if (act) { for (int e = 0; e < NES; ++e) Lr[t * LPAD + e] = po[e]; }
      __syncthreads();
    }
    if (t == 0) {
      __hip_atomic_store(&v[2 * KH],     Lr[SIX(LL, 0)], __ATOMIC_RELEASE, __HIP_MEMORY_SCOPE_AGENT);
      __hip_atomic_store(&v[2 * KH + 1], 0.0f,           __ATOMIC_RELEASE, __HIP_MEMORY_SCOPE_AGENT);
    }
  }

  // ---- last arriving of 129 blocks performs the inverse real DFT ----
  __shared__ int isLast;
  __syncthreads();
  if (t == 0) {
    const int old = __hip_atomic_fetch_add(&cnt[0], 1, __ATOMIC_ACQ_REL, __HIP_MEMORY_SCOPE_AGENT);
    isLast = (old == KH) ? 1 : 0;
  }
  __syncthreads();
  if (isLast) {
    __shared__ float2 twd[256];
    __shared__ float dvr[KF], dvi[KF];
    {
      float sn, cs;
      __sincosf((float)t * 0.0245436926061702596754894014319f, &sn, &cs);  // +2*pi/256
      twd[t] = make_float2(cs, sn);
    }
    if (t < KF) {
      dvr[t] = __hip_atomic_load(&v[2 * t],     __ATOMIC_ACQUIRE, __HIP_MEMORY_SCOPE_AGENT);
      dvi[t] = __hip_atomic_load(&v[2 * t + 1], __ATOMIC_ACQUIRE, __HIP_MEMORY_SCOPE_AGENT);
    }
    if (t == 0) {  // self-reset so every dispatch (incl. rocprof replays) starts clean
      __hip_atomic_store(&cnt[0], 0, __ATOMIC_RELEASE, __HIP_MEMORY_SCOPE_AGENT);
    }
    __syncthreads();
    const float sc = (1.0f / 256.0f) * invCN8();   // undo T-space rescale
    float sum = dvr[0] + ((t & 1) ? -dvr[KH] : dvr[KH]);
    for (int k2 = 1; k2 < KH; ++k2) {
      const int m = (t * k2) & 255;
      const float2 wv = twd[m];
      sum = fmaf(2.0f * dvr[k2], wv.x, sum);
      sum = fmaf(-2.0f * dvi[k2], wv.y, sum);
    }
    outp[t] = sum * sc;
  }
}

extern "C" void kernel_launch(void* const* d_in, const int* in_sizes, int n_in,
                              void* d_out, int out_size, void* d_ws, size_t ws_size,
                              hipStream_t stream) {
  (void)in_sizes; (void)n_in; (void)out_size; (void)ws_size;
  const int*   seq  = (const int*)d_in[0];
  const float* hemb = (const float*)d_in[1];
  const float* slog = (const float*)d_in[2];
  float* ws   = (float*)d_ws;
  float* Q    = ws + Q_OFF;
  float* v    = ws + V_OFF;
  int*   cnt  = (int*)(ws + CNT_OFF);
  float* o    = (float*)d_out;

  hipLaunchKernelGGL(kq,    dim3(LL * AA), dim3(256), 0, stream, hemb, slog, Q, cnt);
  hipLaunchKernelGGL(kmain, dim3(KF),      dim3(256), 0, stream, seq, Q, v, cnt, o);
}

// Round 8
// 95.858 us; speedup vs baseline: 1.7402x; 1.0271x over previous
//
#include <hip/hip_runtime.h>
#include <math.h>

#define LL 8
#define AA 4
#define DD 256
#define KF 129            // frequencies 0..128
#define KH 128            // complex frequencies 0..127; k=128 real (Nyquist)
#define CLEN 64           // steps per chunk (one chunk per thread)
#define NES 36            // strict-lower entries, rows 1..8 (unit diagonal implicit)
#define LPAD 37           // padded slot stride

typedef float v2f __attribute__((ext_vector_type(2)));

#define SIX(l2,l1) ((((l2)*((l2)-1))>>1) + (l1))     // l2 in 1..8, l1 < l2
#define SLOT(s)    ((s)*LPAD + ((s)>>1))             // complex slot base (v2f units)

// ws layout in floats: v[258], then cnt (1 int)
#define V_OFF   0
#define CNT_OFF (2 * KF)

// T-space rescale: S_d[l] = T_d[l] / C(d,l); output row 8 needs 1/C(16384,8)
__device__ __forceinline__ float invCN8() {
  constexpr double c = (16384.0 * 16383.0 * 16382.0 * 16381.0 *
                        16380.0 * 16379.0 * 16378.0 * 16377.0) / 40320.0;
  return (float)(1.0 / c);
}

// acc += b (complex mul) a   -- packed
__device__ __forceinline__ v2f cfma(const v2f b, const v2f a, v2f acc) {
  const v2f bb = (v2f){ b.x,  b.x};
  const v2f bw = (v2f){-b.y,  b.y};
  const v2f as = (v2f){ a.y,  a.x};
  acc = __builtin_elementwise_fma(bb, a,  acc);
  acc = __builtin_elementwise_fma(bw, as, acc);
  return acc;
}

// column-split product of unit-lower-triangular ops: C = B*A (B is the later op)
template <unsigned MASK>
__device__ __forceinline__ void prodCols(const v2f* __restrict__ A, const v2f* __restrict__ B,
                                         v2f (&o)[NES]) {
#pragma unroll
  for (int l1 = 0; l1 < 8; ++l1) {
    if ((MASK >> l1) & 1) {
#pragma unroll
      for (int l2 = l1 + 1; l2 <= 8; ++l2) {
        v2f acc = A[SIX(l2, l1)] + B[SIX(l2, l1)];
#pragma unroll
        for (int m = l1 + 1; m < l2; ++m) acc = cfma(B[SIX(l2, m)], A[SIX(m, l1)], acc);
        o[SIX(l2, l1)] = acc;
      }
    }
  }
}

template <unsigned MASK>
__device__ __forceinline__ void writeCols(v2f* __restrict__ D, const v2f (&o)[NES]) {
#pragma unroll
  for (int l1 = 0; l1 < 8; ++l1) {
    if ((MASK >> l1) & 1) {
#pragma unroll
      for (int l2 = l1 + 1; l2 <= 8; ++l2) D[SIX(l2, l1)] = o[SIX(l2, l1)];
    }
  }
}

// full product with register-array A (earlier) and LDS B (later): o = B*A
__device__ __forceinline__ void prodFullRA(const v2f (&A)[NES], const v2f* __restrict__ B,
                                           v2f (&o)[NES]) {
#pragma unroll
  for (int l1 = 0; l1 < 8; ++l1) {
#pragma unroll
    for (int l2 = l1 + 1; l2 <= 8; ++l2) {
      v2f acc = A[SIX(l2, l1)] + B[SIX(l2, l1)];
#pragma unroll
      for (int m = l1 + 1; m < l2; ++m) acc = cfma(B[SIX(l2, m)], A[SIX(m, l1)], acc);
      o[SIX(l2, l1)] = acc;
    }
  }
}

// real full product, strict-lower unit-triangular
__device__ __forceinline__ void prodR(const float* __restrict__ A, const float* __restrict__ B,
                                      float (&o)[NES]) {
#pragma unroll
  for (int l1 = 0; l1 < 8; ++l1) {
#pragma unroll
    for (int l2 = l1 + 1; l2 <= 8; ++l2) {
      float acc = A[SIX(l2, l1)] + B[SIX(l2, l1)];
#pragma unroll
      for (int m = l1 + 1; m < l2; ++m) acc = fmaf(B[SIX(l2, m)], A[SIX(m, l1)], acc);
      o[SIX(l2, l1)] = acc;
    }
  }
}

// ---------------- single main kernel: per-frequency everything -------------------------------
// 129 blocks x 256 thr. Block k<128: in-block Q (softmax+DFT at k), chunk phase (thread=chunk,
// 64 steps, LDS Q-table), level-1 pair combine, column-split tree 128->8, apply to e0.
// Block 128: Nyquist real path. Last-arriving block does the inverse DFT.
__global__ __launch_bounds__(256, 1) void kmain(const int* __restrict__ seq,
                                                const float* __restrict__ hemb,
                                                const float* __restrict__ slog,
                                                float* __restrict__ v,
                                                int* __restrict__ cnt,
                                                float* __restrict__ outp) {
  const int blk = blockIdx.x;    // 0..128
  const int t   = threadIdx.x;   // 0..255
  __shared__ __align__(16) float ldsf[9600];   // 38400 B: 128 complex slots / 256 real slots
  __shared__ __align__(16) float4 qtab[LL * AA];
  __shared__ float2 twd[256];
  __shared__ float dvr[KF], dvi[KF];
  __shared__ int isLast;

  // twiddle table (positive angle): twd[m] = (cos, sin)(+2*pi*m/256)
  {
    float sn, cs;
    __sincosf((float)t * 0.0245436926061702596754894014319f, &sn, &cs);
    twd[t] = make_float2(cs, sn);
  }
  __syncthreads();

  // ================= in-block Q phase =================
  // row r = l*4+c handled by 8-lane group; lane g8 covers j = u*32 + g8*4 + w
  {
    const int r  = t >> 3;
    const int g8 = t & 7;
    float4 hv[8];
#pragma unroll
    for (int u = 0; u < 8; ++u)
      hv[u] = *(const float4*)(hemb + r * DD + u * 32 + g8 * 4);
    float mx = -1e30f;
#pragma unroll
    for (int u = 0; u < 8; ++u) {
      mx = fmaxf(mx, fmaxf(fmaxf(hv[u].x, hv[u].y), fmaxf(hv[u].z, hv[u].w)));
    }
    mx = fmaxf(mx, __shfl_xor(mx, 1));
    mx = fmaxf(mx, __shfl_xor(mx, 2));
    mx = fmaxf(mx, __shfl_xor(mx, 4));

    float sum = 0.0f, cr = 0.0f, ci = 0.0f;
    if (blk < KH) {
      const int k = blk;
#pragma unroll
      for (int u = 0; u < 8; ++u) {
        const float ev[4] = {expf(hv[u].x - mx), expf(hv[u].y - mx),
                             expf(hv[u].z - mx), expf(hv[u].w - mx)};
#pragma unroll
        for (int w = 0; w < 4; ++w) {
          const int j = u * 32 + g8 * 4 + w;
          const int m = (j * k) & 255;
          const float2 tv = twd[m];
          sum += ev[w];
          cr = fmaf(ev[w], tv.x, cr);
          ci = fmaf(-ev[w], tv.y, ci);    // negative-angle sin
        }
      }
    } else {
      // Nyquist: w^j = (-1)^j, parity of j is parity of w
#pragma unroll
      for (int u = 0; u < 8; ++u) {
        const float ev[4] = {expf(hv[u].x - mx), expf(hv[u].y - mx),
                             expf(hv[u].z - mx), expf(hv[u].w - mx)};
        sum += ev[0] + ev[1] + ev[2] + ev[3];
        cr  += (ev[0] - ev[1]) + (ev[2] - ev[3]);
      }
    }
    sum += __shfl_xor(sum, 1); cr += __shfl_xor(cr, 1); ci += __shfl_xor(ci, 1);
    sum += __shfl_xor(sum, 2); cr += __shfl_xor(cr, 2); ci += __shfl_xor(ci, 2);
    sum += __shfl_xor(sum, 4); cr += __shfl_xor(cr, 4); ci += __shfl_xor(ci, 4);

    if (g8 == 0) {
      const float sl = slog[r];
      const float sg = 1.0f / (1.0f + expf(-sl));
      const float q  = fmaf(2.0f, sg, -1.0f);      // 2*sigmoid - 1
      const float sc = q / sum;
      const float qr = cr * sc;
      const float qi = ci * sc;
      qtab[r] = make_float4(qr, qr, -qi, qi);      // (qr, qr, -qi, qi); Nyquist uses .x
    }
  }
  __syncthreads();

  if (blk < KH) {
    // ================= complex path, k = blk =================
    const int k = blk;

    // ---- chunk phase: 64 steps, symbols per-lane, Q via LDS table ----
    v2f G[NES];
#pragma unroll
    for (int e = 0; e < NES; ++e) G[e] = (v2f){0.f, 0.f};   // identity op

    const int4* sp = (const int4*)(seq + t * CLEN);
    for (int sb = 0; sb < CLEN / 4; ++sb) {
      const int4 cs = sp[sb];
      const int csy[4] = {cs.x, cs.y, cs.z, cs.w};
#pragma unroll
      for (int u = 0; u < 4; ++u) {
        const int c = csy[u];
        float4 qv[LL];
#pragma unroll
        for (int l = 0; l < LL; ++l) qv[l] = qtab[(l << 2) | c];
#pragma unroll
        for (int l = LL; l >= 1; --l) {          // descending: row l reads OLD row l-1
          const float4 q4 = qv[l - 1];
          const v2f qa = (v2f){q4.x, q4.y};      // (qr, qr)
          const v2f qb = (v2f){q4.z, q4.w};      // (-qi, qi)
          {
            v2f g = G[SIX(l, l - 1)];
            g.x += q4.x; g.y += q4.w;            // += (qr, qi)
            G[SIX(l, l - 1)] = g;
          }
#pragma unroll
          for (int l1 = 0; l1 < l - 1; ++l1) {
            const v2f H  = G[SIX(l - 1, l1)];
            const v2f Hs = (v2f){H.y, H.x};
            v2f g = G[SIX(l, l1)];
            g = __builtin_elementwise_fma(qa, H,  g);
            g = __builtin_elementwise_fma(qb, Hs, g);
            G[SIX(l, l1)] = g;
          }
        }
      }
    }

    // ---- level 1: 256 ops -> 128 slots in LDS ----
    v2f* L = (v2f*)ldsf;
    if (t & 1) {                       // odd chunk (later of the pair) -> LDS
      v2f* D = L + SLOT(t >> 1);
#pragma unroll
      for (int e = 0; e < NES; ++e) D[e] = G[e];
    }
    __syncthreads();
    if (!(t & 1)) {                    // even chunk combines: C = B(odd) * A(even)
      v2f o[NES];
      prodFullRA(G, L + SLOT(t >> 1), o);
      v2f* D = L + SLOT(t >> 1);
#pragma unroll
      for (int e = 0; e < NES; ++e) D[e] = o[e];
    }
    __syncthreads();

    // ---- column-split tree: 128 -> 64 -> 32 -> 16 -> 8 ----
    const int w = t >> 6;
    const int j = t & 63;
    v2f pc[NES];
    for (int n = 64; n >= 8; n >>= 1) {
      const bool act = (j < n);
      if (act) {
        const v2f* Ab = L + SLOT(2 * j);
        const v2f* Bb = L + SLOT(2 * j + 1);
        switch (w) {
          case 0:  prodCols<0x01>(Ab, Bb, pc); break;
          case 1:  prodCols<0x42>(Ab, Bb, pc); break;
          case 2:  prodCols<0x14>(Ab, Bb, pc); break;
          default: prodCols<0xA8>(Ab, Bb, pc); break;
        }
      }
      __syncthreads();
      if (act) {
        v2f* Db = L + SLOT(j);
        switch (w) {
          case 0:  writeCols<0x01>(Db, pc); break;
          case 1:  writeCols<0x42>(Db, pc); break;
          case 2:  writeCols<0x14>(Db, pc); break;
          default: writeCols<0xA8>(Db, pc); break;
        }
      }
      __syncthreads();
    }

    // ---- apply 8 remaining ops to e0 (wave 0; lane l holds row l) ----
    if (t < 64) {
      v2f sv[LL + 1];
      sv[0] = (v2f){1.f, 0.f};
#pragma unroll
      for (int l = 1; l <= LL; ++l) sv[l] = (v2f){0.f, 0.f};
      for (int gg = 0; gg < 8; ++gg) {
        v2f nv = (v2f){0.f, 0.f};
        if (t >= 1 && t <= LL) {
          nv = sv[t];                               // unit diagonal
          const v2f* Bb = L + SLOT(gg);
          const int rb = (t * (t - 1)) >> 1;        // SIX(t, 0)
#pragma unroll
          for (int l1 = 0; l1 < 8; ++l1) {
            if (l1 < t) nv = cfma(Bb[rb + l1], sv[l1], nv);
          }
        }
#pragma unroll
        for (int l = 1; l <= LL; ++l) {
          sv[l].x = __shfl(nv.x, l);
          sv[l].y = __shfl(nv.y, l);
        }
      }
      if (t == 0) {
        __hip_atomic_store(&v[2 * k],     sv[LL].x, __ATOMIC_RELEASE, __HIP_MEMORY_SCOPE_AGENT);
        __hip_atomic_store(&v[2 * k + 1], sv[LL].y, __ATOMIC_RELEASE, __HIP_MEMORY_SCOPE_AGENT);
      }
    }
  } else {
    // ================= Nyquist (k = 128, real) =================
    float* Lr = ldsf;                       // [256 slots][LPAD] floats
    float Q8[LL][AA];
#pragma unroll
    for (int lc = 0; lc < LL * AA; ++lc) Q8[lc >> 2][lc & 3] = qtab[lc].x;

    float Gr[NES];
#pragma unroll
    for (int e = 0; e < NES; ++e) Gr[e] = 0.f;

    const int4* sp = (const int4*)(seq + t * CLEN);
    for (int sb = 0; sb < CLEN / 4; ++sb) {
      const int4 cs = sp[sb];
      const int csy[4] = {cs.x, cs.y, cs.z, cs.w};
#pragma unroll
      for (int u = 0; u < 4; ++u) {
        const int c = csy[u];
        float Qs[LL];
#pragma unroll
        for (int l = 0; l < LL; ++l) {
          const float qa = (c & 1) ? Q8[l][1] : Q8[l][0];
          const float qb = (c & 1) ? Q8[l][3] : Q8[l][2];
          Qs[l] = (c & 2) ? qb : qa;
        }
#pragma unroll
        for (int l = LL; l >= 1; --l) {
          Gr[SIX(l, l - 1)] += Qs[l - 1];
#pragma unroll
          for (int l1 = 0; l1 < l - 1; ++l1)
            Gr[SIX(l, l1)] = fmaf(Qs[l - 1], Gr[SIX(l - 1, l1)], Gr[SIX(l, l1)]);
        }
      }
    }
#pragma unroll
    for (int e = 0; e < NES; ++e) Lr[t * LPAD + e] = Gr[e];
    __syncthreads();

    float po[NES];
    for (int n = 128; n >= 1; n >>= 1) {   // 256 -> 1 in-place pair tree
      const bool act = (t < n);
      if (act) prodR(Lr + (2 * t) * LPAD, Lr + (2 * t + 1) * LPAD, po);
      __syncthreads();
      if (act) { for (int e = 0; e < NES; ++e) Lr[t * LPAD + e] = po[e]; }
      __syncthreads();
    }
    if (t == 0) {
      __hip_atomic_store(&v[2 * KH],     Lr[SIX(LL, 0)], __ATOMIC_RELEASE, __HIP_MEMORY_SCOPE_AGENT);
      __hip_atomic_store(&v[2 * KH + 1], 0.0f,           __ATOMIC_RELEASE, __HIP_MEMORY_SCOPE_AGENT);
    }
  }

  // ---- last arriving of 129 blocks performs the inverse real DFT ----
  __syncthreads();
  if (t == 0) {
    const int old = __hip_atomic_fetch_add(&cnt[0], 1, __ATOMIC_ACQ_REL, __HIP_MEMORY_SCOPE_AGENT);
    isLast = (old == KH) ? 1 : 0;
  }
  __syncthreads();
  if (isLast) {
    if (t < KF) {
      dvr[t] = __hip_atomic_load(&v[2 * t],     __ATOMIC_ACQUIRE, __HIP_MEMORY_SCOPE_AGENT);
      dvi[t] = __hip_atomic_load(&v[2 * t + 1], __ATOMIC_ACQUIRE, __HIP_MEMORY_SCOPE_AGENT);
    }
    if (t == 0) {  // self-reset so every dispatch (incl. rocprof replays) starts clean
      __hip_atomic_store(&cnt[0], 0, __ATOMIC_RELEASE, __HIP_MEMORY_SCOPE_AGENT);
    }
    __syncthreads();
    const float sc = (1.0f / 256.0f) * invCN8();   // undo T-space rescale
    float sum = dvr[0] + ((t & 1) ? -dvr[KH] : dvr[KH]);
    for (int k2 = 1; k2 < KH; ++k2) {
      const int m = (t * k2) & 255;
      const float2 wv = twd[m];
      sum = fmaf(2.0f * dvr[k2], wv.x, sum);
      sum = fmaf(-2.0f * dvi[k2], wv.y, sum);
    }
    outp[t] = sum * sc;
  }
}

extern "C" void kernel_launch(void* const* d_in, const int* in_sizes, int n_in,
                              void* d_out, int out_size, void* d_ws, size_t ws_size,
                              hipStream_t stream) {
  (void)in_sizes; (void)n_in; (void)out_size; (void)ws_size;
  const int*   seq  = (const int*)d_in[0];
  const float* hemb = (const float*)d_in[1];
  const float* slog = (const float*)d_in[2];
  float* ws   = (float*)d_ws;
  float* v    = ws + V_OFF;
  int*   cnt  = (int*)(ws + CNT_OFF);
  float* o    = (float*)d_out;

  hipMemsetAsync(cnt, 0, sizeof(int), stream);   // stream-ordered, graph-capture-safe
  hipLaunchKernelGGL(kmain, dim3(KF), dim3(256), 0, stream, seq, hemb, slog, v, cnt, o);
}